// Round 5
// baseline (74.787 us; speedup 1.0000x reference)
//
#include <hip/hip_runtime.h>
#include <hip/hip_bf16.h>

#define A_ 8
#define B_ 256
#define I_ 256
#define J_ 256
#define K_ 256

typedef __attribute__((ext_vector_type(8))) short short8_t;
typedef __attribute__((ext_vector_type(4))) float f32x4_t;
typedef __attribute__((ext_vector_type(4))) uint u32x4_t;

static __device__ __forceinline__ uint pack2bf(float a, float b) {
  float2 f2; f2.x = a; f2.y = b;
  __hip_bfloat162 h2 = __float22bfloat162_rn(f2);
  uint r;
  __builtin_memcpy(&r, &h2, 4);
  return r;
}

static __device__ __forceinline__ ushort f2bf(float f) {
  __hip_bfloat16 h = __float2bfloat16(f);
  ushort us;
  __builtin_memcpy(&us, &h, 2);
  return us;
}

static __device__ __forceinline__ float bf2f(ushort h) {
  uint u = ((uint)h) << 16;
  float f;
  __builtin_memcpy(&f, &u, 4);
  return f;
}

// ---------------------------------------------------------------------------
// Prepass C: cbf[b][j] = bf16(c[b][j])
// ---------------------------------------------------------------------------
__global__ __launch_bounds__(256) void prepass_c_kernel(
    const float* __restrict__ c, ushort* __restrict__ cbf) {
  const int idx = blockIdx.x * 256 + threadIdx.x;
  const f32x4_t v = *reinterpret_cast<const f32x4_t*>(c + (size_t)idx * 4);
  uint2 r;
  r.x = pack2bf(v[0], v[1]);
  r.y = pack2bf(v[2], v[3]);
  *reinterpret_cast<uint2*>(cbf + (size_t)idx * 4) = r;
}

// ---------------------------------------------------------------------------
// Prepass W: wt[i][k][j] = bf16(w[i][j][k])  — one-time global transpose.
// Block per i. Chunks of 32 j-rows; LDS T[k][jpair] uint (pair-packed bf16),
// coalesced fp32 reads, 64B-aligned contiguous bf16 writes.
// ---------------------------------------------------------------------------
__global__ __launch_bounds__(256, 2) void prepass_w_kernel(
    const float* __restrict__ w, ushort* __restrict__ wt) {
  const int i   = blockIdx.x;
  const int tid = threadIdx.x;
  const int jp  = tid & 15;   // j-pair index within chunk
  const int ks  = tid >> 4;   // k-segment of 16
  __shared__ uint T[256][17];  // [k][jpair], padded (17 coprime-ish banks)

  const float* wi  = w  + (size_t)i * (J_ * K_);
  ushort*      wti = wt + (size_t)i * (J_ * K_);

  for (int jc = 0; jc < 8; ++jc) {
    const int j = jc * 32 + jp * 2;
    f32x4_t r0[4], r1[4];
#pragma unroll
    for (int q = 0; q < 4; q++) {
      r0[q] = *reinterpret_cast<const f32x4_t*>(wi + (size_t)j * K_ + ks * 16 + q * 4);
      r1[q] = *reinterpret_cast<const f32x4_t*>(wi + (size_t)(j + 1) * K_ + ks * 16 + q * 4);
    }
    if (jc) __syncthreads();  // prev read-phase done before overwriting T
#pragma unroll
    for (int q = 0; q < 4; q++)
#pragma unroll
      for (int e = 0; e < 4; e++)
        T[ks * 16 + q * 4 + e][jp] = pack2bf(r0[q][e], r1[q][e]);
    __syncthreads();
    // write phase: thread = one k row; 32 contiguous j halves (64B aligned)
    uint row[16];
#pragma unroll
    for (int p = 0; p < 16; p++) row[p] = T[tid][p];
#pragma unroll
    for (int q = 0; q < 4; q++) {
      u32x4_t v;
#pragma unroll
      for (int e = 0; e < 4; e++) v[e] = row[q * 4 + e];
      *reinterpret_cast<u32x4_t*>(wti + (size_t)tid * J_ + jc * 32 + q * 8) = v;
    }
  }
}

// ---------------------------------------------------------------------------
// Pass 1 (direct): u[b][i][k] = sum_j c[b][j] * w[i][j][k]
// Grid (i, k-quarter) = (256,4). 256 threads = 4 waves, each 64(b) x 64(k).
// NO LDS, NO barriers: both operands b128-loaded straight from global
// (cbf L2-hot; wt j-contiguous), ping-pong register prefetch, waves slip.
// ---------------------------------------------------------------------------
__global__ __launch_bounds__(256, 2) void pass1_kernel(
    const ushort* __restrict__ cbf, const ushort* __restrict__ wt,
    ushort* __restrict__ u) {
  const int i    = blockIdx.x;
  const int k0   = blockIdx.y * 64;
  const int tid  = threadIdx.x;
  const int lane = tid & 63;
  const int wave = tid >> 6;   // b-quadrant
  const int lrow = lane & 15;
  const int lhi  = lane >> 4;  // 0..3

  const ushort* wtik = wt + ((size_t)i * K_ + k0) * J_;  // wt[i][k0+...][j]
  const int arow = wave * 64 + lrow;

  f32x4_t acc[4][4];
#pragma unroll
  for (int m = 0; m < 4; m++)
#pragma unroll
    for (int n = 0; n < 4; n++) acc[m][n] = (f32x4_t)(0.0f);

  short8_t af[2][4], bfr[2][4];

#define LOADSTEP(p, j0)                                                     \
  {                                                                         \
    _Pragma("unroll") for (int m = 0; m < 4; m++)                           \
        af[p][m] = *reinterpret_cast<const short8_t*>(                      \
            cbf + (size_t)(arow + m * 16) * J_ + (j0) + lhi * 8);           \
    _Pragma("unroll") for (int n = 0; n < 4; n++)                           \
        bfr[p][n] = *reinterpret_cast<const short8_t*>(                     \
            wtik + (size_t)(n * 16 + lrow) * J_ + (j0) + lhi * 8);          \
  }

  LOADSTEP(0, 0);
#pragma unroll
  for (int t = 0; t < 8; ++t) {
    const int cur = t & 1;
    if (t < 7) LOADSTEP(cur ^ 1, (t + 1) * 32);
#pragma unroll
    for (int m = 0; m < 4; m++)
#pragma unroll
      for (int n = 0; n < 4; n++)
        acc[m][n] = __builtin_amdgcn_mfma_f32_16x16x32_bf16(
            af[cur][m], bfr[cur][n], acc[m][n], 0, 0, 0);
  }
#undef LOADSTEP

  // epilogue: u[b][i][k] bf16
#pragma unroll
  for (int m = 0; m < 4; m++) {
    const int brow = wave * 64 + m * 16 + lhi * 4;
#pragma unroll
    for (int n = 0; n < 4; n++) {
      const int kc = k0 + n * 16 + lrow;
      ushort* up = u + ((size_t)brow * I_ + i) * K_ + kc;
#pragma unroll
      for (int r = 0; r < 4; r++)
        up[(size_t)r * (I_ * K_)] = f2bf(acc[m][n][r]);
    }
  }
}

// ---------------------------------------------------------------------------
// Pass 1 (LDS fallback, = round-3 kernel): used when ws can't hold wt.
// ---------------------------------------------------------------------------
#define LDK 40
__global__ __launch_bounds__(256, 2) void pass1_lds_kernel(
    const ushort* __restrict__ cbf, const float* __restrict__ w,
    ushort* __restrict__ u) {
  const int i    = blockIdx.x;
  const int k0   = blockIdx.y * 64;
  const int tid  = threadIdx.x;
  const int lane = tid & 63;
  const int wave = tid >> 6;
  const int lrow = lane & 15;
  const int lhi  = lane >> 4;

  __shared__ ushort Bt[2][64][LDK];
  const float* wi = w + (size_t)i * (J_ * K_) + k0;
  const int jp = tid & 15;
  const int kq = tid >> 4;
  const int arow = wave * 64 + lrow;

  f32x4_t acc[4][4];
#pragma unroll
  for (int m = 0; m < 4; m++)
#pragma unroll
    for (int n = 0; n < 4; n++) acc[m][n] = (f32x4_t)(0.0f);

  f32x4_t  bv[2][2];
  short8_t af[2][4];

#define LOADB(p, j0)                                                        \
  {                                                                         \
    _Pragma("unroll") for (int jj = 0; jj < 2; jj++)                        \
        bv[p][jj] = *reinterpret_cast<const f32x4_t*>(                      \
            wi + (size_t)((j0) + jp * 2 + jj) * K_ + kq * 4);               \
  }
#define LOADA(p, j0)                                                        \
  {                                                                         \
    _Pragma("unroll") for (int m = 0; m < 4; m++)                           \
        af[p][m] = *reinterpret_cast<const short8_t*>(                      \
            cbf + (size_t)(arow + m * 16) * J_ + (j0) + lhi * 8);           \
  }
#define STOREB(buf, p)                                                      \
  {                                                                         \
    _Pragma("unroll") for (int kk = 0; kk < 4; kk++)                        \
        *reinterpret_cast<uint*>(&Bt[buf][kq * 4 + kk][jp * 2]) =           \
            pack2bf(bv[p][0][kk], bv[p][1][kk]);                            \
  }

  LOADB(0, 0);
  LOADA(0, 0);
  STOREB(0, 0);
  __syncthreads();

#pragma unroll
  for (int t = 0; t < 8; ++t) {
    const int cur = t & 1;
    const int nxt = cur ^ 1;
    if (t < 7) {
      LOADB(nxt, (t + 1) * 32);
      LOADA(nxt, (t + 1) * 32);
    }
    short8_t bfr[4];
#pragma unroll
    for (int n = 0; n < 4; n++)
      bfr[n] = *reinterpret_cast<const short8_t*>(
          &Bt[cur][n * 16 + lrow][lhi * 8]);
#pragma unroll
    for (int m = 0; m < 4; m++)
#pragma unroll
      for (int n = 0; n < 4; n++)
        acc[m][n] = __builtin_amdgcn_mfma_f32_16x16x32_bf16(
            af[cur][m], bfr[n], acc[m][n], 0, 0, 0);
    if (t < 7) STOREB(nxt, nxt);
    __syncthreads();
  }

#pragma unroll
  for (int m = 0; m < 4; m++) {
    const int brow = wave * 64 + m * 16 + lhi * 4;
#pragma unroll
    for (int n = 0; n < 4; n++) {
      const int kc = k0 + n * 16 + lrow;
      ushort* up = u + ((size_t)brow * I_ + i) * K_ + kc;
#pragma unroll
      for (int r = 0; r < 4; r++)
        up[(size_t)r * (I_ * K_)] = f2bf(acc[m][n][r]);
    }
  }
#undef LOADB
#undef LOADA
#undef STOREB
}

// ---------------------------------------------------------------------------
// Pass 2: out[a][b][k] = sum_i s[a][b][i] * u[b][i][k] + bias[k]
// (round-3 proven version) Grid (B, 2): block handles 4 a's.
// ---------------------------------------------------------------------------
__global__ __launch_bounds__(256) void pass2_kernel(
    const float* __restrict__ s, const ushort* __restrict__ u,
    const float* __restrict__ bias, float* __restrict__ out) {
  const int b   = blockIdx.x;
  const int a0  = blockIdx.y * 4;
  const int tid = threadIdx.x;
  __shared__ float s_l[4][I_];
  __shared__ float red[8][4][K_];

#pragma unroll
  for (int v = 0; v < 4; v++) {
    const int idx = tid + v * 256;
    const int a = idx >> 8, ii = idx & 255;
    s_l[a][ii] = s[((size_t)(a0 + a) * B_ + b) * I_ + ii];
  }
  __syncthreads();

  const int kb = (tid & 31) * 8;
  const int ig = tid >> 5;
  float acc[4][8];
#pragma unroll
  for (int a = 0; a < 4; a++)
#pragma unroll
    for (int q = 0; q < 8; q++) acc[a][q] = 0.0f;

  const ushort* ub = u + ((size_t)b * I_ + ig * 32) * K_ + kb;
  for (int ii = 0; ii < 32; ++ii) {
    const short8_t uv = *reinterpret_cast<const short8_t*>(ub + (size_t)ii * K_);
    float f[8];
#pragma unroll
    for (int q = 0; q < 8; q++) f[q] = bf2f((ushort)uv[q]);
    const int i = ig * 32 + ii;
#pragma unroll
    for (int a = 0; a < 4; a++) {
      const float sa = s_l[a][i];
#pragma unroll
      for (int q = 0; q < 8; q++) acc[a][q] += sa * f[q];
    }
  }

#pragma unroll
  for (int a = 0; a < 4; a++) {
    f32x4_t r0, r1;
#pragma unroll
    for (int q = 0; q < 4; q++) { r0[q] = acc[a][q]; r1[q] = acc[a][4 + q]; }
    *reinterpret_cast<f32x4_t*>(&red[ig][a][kb])     = r0;
    *reinterpret_cast<f32x4_t*>(&red[ig][a][kb + 4]) = r1;
  }
  __syncthreads();

#pragma unroll
  for (int v = 0; v < 4; v++) {
    const int k = tid;
    float sum = 0.0f;
#pragma unroll
    for (int g = 0; g < 8; g++) sum += red[g][v][k];
    out[((size_t)(a0 + v) * B_ + b) * K_ + k] = sum + bias[k];
  }
}

// ---------------------------------------------------------------------------
// Fallback (slow but correct, fp32).
// ---------------------------------------------------------------------------
__global__ __launch_bounds__(256) void fallback_kernel(
    const float* __restrict__ s, const float* __restrict__ cmat,
    const float* __restrict__ w, const float* __restrict__ bias,
    float* __restrict__ out) {
  const int b = blockIdx.x;
  const int k = threadIdx.x;
  __shared__ float c_l[J_];
  __shared__ float s_l[A_][I_];
  for (int idx = threadIdx.x; idx < J_; idx += 256) c_l[idx] = cmat[(size_t)b * J_ + idx];
  for (int idx = threadIdx.x; idx < A_ * I_; idx += 256) {
    const int a = idx >> 8;
    const int i = idx & 255;
    s_l[a][i] = s[(size_t)a * (B_ * I_) + (size_t)b * I_ + i];
  }
  __syncthreads();
  float acc[A_];
#pragma unroll
  for (int a = 0; a < A_; a++) acc[a] = 0.0f;
  for (int i = 0; i < I_; i++) {
    const float* wrow = w + (size_t)i * (J_ * K_) + k;
    float inner = 0.0f;
    for (int j = 0; j < J_; j++) inner += c_l[j] * wrow[(size_t)j * K_];
#pragma unroll
    for (int a = 0; a < A_; a++) acc[a] += s_l[a][i] * inner;
  }
#pragma unroll
  for (int a = 0; a < A_; a++)
    out[((size_t)a * B_ + b) * K_ + k] = acc[a] + bias[k];
}

extern "C" void kernel_launch(void* const* d_in, const int* in_sizes, int n_in,
                              void* d_out, int out_size, void* d_ws, size_t ws_size,
                              hipStream_t stream) {
  const float* s    = (const float*)d_in[0];  // (A,B,I)
  const float* cmat = (const float*)d_in[1];  // (B,J)
  const float* w    = (const float*)d_in[2];  // (I,J,K)
  const float* bias = (const float*)d_in[3];  // (K,)
  float* out = (float*)d_out;

  const size_t u_elems  = (size_t)B_ * I_ * K_;   // 16.7M halves
  const size_t wt_elems = (size_t)I_ * J_ * K_;   // 16.7M halves
  const size_t cbf_elems = (size_t)B_ * J_;
  const size_t need_full = (u_elems + wt_elems + cbf_elems) * sizeof(ushort);
  const size_t need_mid  = (u_elems + cbf_elems) * sizeof(ushort);

  if (ws_size >= need_full) {
    ushort* u   = (ushort*)d_ws;
    ushort* wt  = (ushort*)d_ws + u_elems;
    ushort* cbf = (ushort*)d_ws + u_elems + wt_elems;
    prepass_c_kernel<<<dim3((B_ * J_) / (256 * 4)), dim3(256), 0, stream>>>(cmat, cbf);
    prepass_w_kernel<<<dim3(I_), dim3(256), 0, stream>>>(w, wt);
    pass1_kernel<<<dim3(I_, 4), dim3(256), 0, stream>>>(cbf, wt, u);
    pass2_kernel<<<dim3(B_, 2), dim3(256), 0, stream>>>(s, u, bias, out);
  } else if (ws_size >= need_mid) {
    ushort* u   = (ushort*)d_ws;
    ushort* cbf = (ushort*)d_ws + u_elems;
    prepass_c_kernel<<<dim3((B_ * J_) / (256 * 4)), dim3(256), 0, stream>>>(cmat, cbf);
    pass1_lds_kernel<<<dim3(I_, 4), dim3(256), 0, stream>>>(cbf, w, u);
    pass2_kernel<<<dim3(B_, 2), dim3(256), 0, stream>>>(s, u, bias, out);
  } else {
    fallback_kernel<<<dim3(B_), dim3(256), 0, stream>>>(s, cmat, w, bias, out);
  }
}

// Round 6
// 59.073 us; speedup vs baseline: 1.2660x; 1.2660x over previous
//
#include <hip/hip_runtime.h>
#include <hip/hip_bf16.h>

#define A_ 8
#define B_ 256
#define I_ 256
#define J_ 256
#define K_ 256

typedef __attribute__((ext_vector_type(8))) short short8_t;
typedef __attribute__((ext_vector_type(4))) float f32x4_t;
typedef __attribute__((ext_vector_type(4))) uint u32x4_t;

static __device__ __forceinline__ uint pack2bf(float a, float b) {
  float2 f2; f2.x = a; f2.y = b;
  __hip_bfloat162 h2 = __float22bfloat162_rn(f2);
  uint r;
  __builtin_memcpy(&r, &h2, 4);
  return r;
}

static __device__ __forceinline__ ushort f2bf(float f) {
  __hip_bfloat16 h = __float2bfloat16(f);
  ushort us;
  __builtin_memcpy(&us, &h, 2);
  return us;
}

static __device__ __forceinline__ float bf2f(ushort h) {
  uint u = ((uint)h) << 16;
  float f;
  __builtin_memcpy(&f, &u, 4);
  return f;
}

// async global -> LDS, 16 bytes per lane (dest = wave-uniform base + lane*16)
static __device__ __forceinline__ void gl2lds16(const void* g, void* l) {
  __builtin_amdgcn_global_load_lds(
      (const __attribute__((address_space(1))) uint*)g,
      (__attribute__((address_space(3))) uint*)l, 16, 0, 0);
}

// ---------------------------------------------------------------------------
// Prepass C: cbf[b][j] = bf16(c[b][j])
// ---------------------------------------------------------------------------
__global__ __launch_bounds__(256) void prepass_c_kernel(
    const float* __restrict__ c, ushort* __restrict__ cbf) {
  const int idx = blockIdx.x * 256 + threadIdx.x;
  const f32x4_t v = *reinterpret_cast<const f32x4_t*>(c + (size_t)idx * 4);
  uint2 r;
  r.x = pack2bf(v[0], v[1]);
  r.y = pack2bf(v[2], v[3]);
  *reinterpret_cast<uint2*>(cbf + (size_t)idx * 4) = r;
}

// ---------------------------------------------------------------------------
// Prepass W: wt[i][k][j] = bf16(w[i][j][k]) — one-time transpose+convert.
// Grid (i=256, jc=8) = 2048 blocks (6-8/CU). Block: 32 j-rows x 256 k.
// ---------------------------------------------------------------------------
__global__ __launch_bounds__(256, 6) void prepass_w_kernel(
    const float* __restrict__ w, ushort* __restrict__ wt) {
  const int i   = blockIdx.x;
  const int jc  = blockIdx.y;
  const int tid = threadIdx.x;
  const int jp  = tid & 15;   // j-pair index within chunk (0..15)
  const int ks  = tid >> 4;   // k-segment of 16 (0..15)
  __shared__ uint T[256][17];  // [k][jpair], pair-packed bf16, padded

  const float* wi  = w  + (size_t)i * (J_ * K_);
  ushort*      wti = wt + (size_t)i * (J_ * K_);

  const int j = jc * 32 + jp * 2;
  f32x4_t r0[4], r1[4];
#pragma unroll
  for (int q = 0; q < 4; q++) {
    r0[q] = *reinterpret_cast<const f32x4_t*>(wi + (size_t)j * K_ + ks * 16 + q * 4);
    r1[q] = *reinterpret_cast<const f32x4_t*>(wi + (size_t)(j + 1) * K_ + ks * 16 + q * 4);
  }
#pragma unroll
  for (int q = 0; q < 4; q++)
#pragma unroll
    for (int e = 0; e < 4; e++)
      T[ks * 16 + q * 4 + e][jp] = pack2bf(r0[q][e], r1[q][e]);
  __syncthreads();
  // write: thread = one k row; 32 contiguous j halves (64B, aligned)
  uint row[16];
#pragma unroll
  for (int p = 0; p < 16; p++) row[p] = T[tid][p];
#pragma unroll
  for (int q = 0; q < 4; q++) {
    u32x4_t v;
#pragma unroll
    for (int e = 0; e < 4; e++) v[e] = row[q * 4 + e];
    *reinterpret_cast<u32x4_t*>(wti + (size_t)tid * J_ + jc * 32 + q * 8) = v;
  }
}

// ---------------------------------------------------------------------------
// Pass 1 (m97-style): u[b][i][k] = sum_j c[b][j] * w[i][j][k]
// 1024 blocks (XCD-swizzled: 4 quadrant-blocks of one i share an XCD L2).
// Block: 128b x 128k tile; 4 waves (2x2), wave = 64x64, acc 4x4.
// BK=32. Both tiles staged via global_load_lds dwordx4 (async DMA),
// double-buffered LDS, stage(t+1) issued before MFMA(t), 1 barrier/step.
// ---------------------------------------------------------------------------
__global__ __launch_bounds__(256, 4) void pass1_kernel(
    const ushort* __restrict__ cbf, const ushort* __restrict__ wt,
    ushort* __restrict__ u) {
  // XCD swizzle: launched id L -> work wg so each XCD gets contiguous wg range
  const int wg   = (blockIdx.x & 7) * 128 + (blockIdx.x >> 3);
  const int i    = wg >> 2;
  const int bh   = (wg >> 1) & 1;
  const int kh   = wg & 1;
  const int b0   = bh * 128;
  const int k0g  = kh * 128;
  const int tid  = threadIdx.x;
  const int lane = tid & 63;
  const int wv   = tid >> 6;   // wave 0..3
  const int wr   = wv >> 1;    // b half within tile
  const int wc   = wv & 1;     // k half within tile
  const int lrow = lane & 15;
  const int lhi  = lane >> 4;  // 0..3

  __shared__ ushort As[2][128][32];  // [b][j] bf16, 8KB each
  __shared__ ushort Bs[2][128][32];  // [k][j] bf16, 8KB each

  const ushort* wtik = wt + ((size_t)i * K_ + k0g) * J_;

  // staging source row/col for this lane (per gl_lds instr q = 0/1)
  const int srow = wv * 16 + (lane >> 2);  // + q*64
  const int scol = (lane & 3) * 8;         // halves (16B chunk)

  f32x4_t acc[4][4];
#pragma unroll
  for (int m = 0; m < 4; m++)
#pragma unroll
    for (int n = 0; n < 4; n++) acc[m][n] = (f32x4_t)(0.0f);

#define STAGE(buf, j0)                                                       \
  {                                                                          \
    _Pragma("unroll") for (int q = 0; q < 2; q++) {                          \
      gl2lds16(cbf + (size_t)(b0 + q * 64 + srow) * J_ + (j0) + scol,        \
               &As[buf][0][0] + q * 2048 + wv * 512);                        \
      gl2lds16(wtik + (size_t)(q * 64 + srow) * J_ + (j0) + scol,            \
               &Bs[buf][0][0] + q * 2048 + wv * 512);                        \
    }                                                                        \
  }

  STAGE(0, 0);
  __syncthreads();

#pragma unroll
  for (int t = 0; t < 8; ++t) {
    const int cur = t & 1;
    if (t < 7) STAGE(cur ^ 1, (t + 1) * 32);  // async fill of other buffer
    short8_t af[4], bf[4];
#pragma unroll
    for (int m = 0; m < 4; m++)
      af[m] = *reinterpret_cast<const short8_t*>(
          &As[cur][wr * 64 + m * 16 + lrow][lhi * 8]);
#pragma unroll
    for (int n = 0; n < 4; n++)
      bf[n] = *reinterpret_cast<const short8_t*>(
          &Bs[cur][wc * 64 + n * 16 + lrow][lhi * 8]);
#pragma unroll
    for (int m = 0; m < 4; m++)
#pragma unroll
      for (int n = 0; n < 4; n++)
        acc[m][n] = __builtin_amdgcn_mfma_f32_16x16x32_bf16(af[m], bf[n],
                                                            acc[m][n], 0, 0, 0);
    __syncthreads();  // drains stage(t+1) loads + LDS-read fence
  }
#undef STAGE

  // epilogue: u[b][i][k] bf16
#pragma unroll
  for (int m = 0; m < 4; m++) {
    const int brow = b0 + wr * 64 + m * 16 + lhi * 4;
#pragma unroll
    for (int n = 0; n < 4; n++) {
      const int kc = k0g + wc * 64 + n * 16 + lrow;
      ushort* up = u + ((size_t)brow * I_ + i) * K_ + kc;
#pragma unroll
      for (int r = 0; r < 4; r++)
        up[(size_t)r * (I_ * K_)] = f2bf(acc[m][n][r]);
    }
  }
}

// ---------------------------------------------------------------------------
// Pass 1 (LDS fallback, round-3 kernel): used when ws can't hold wt.
// ---------------------------------------------------------------------------
#define LDK 40
__global__ __launch_bounds__(256, 2) void pass1_lds_kernel(
    const ushort* __restrict__ cbf, const float* __restrict__ w,
    ushort* __restrict__ u) {
  const int i    = blockIdx.x;
  const int k0   = blockIdx.y * 64;
  const int tid  = threadIdx.x;
  const int lane = tid & 63;
  const int wave = tid >> 6;
  const int lrow = lane & 15;
  const int lhi  = lane >> 4;

  __shared__ ushort Bt[2][64][LDK];
  const float* wi = w + (size_t)i * (J_ * K_) + k0;
  const int jp = tid & 15;
  const int kq = tid >> 4;
  const int arow = wave * 64 + lrow;

  f32x4_t acc[4][4];
#pragma unroll
  for (int m = 0; m < 4; m++)
#pragma unroll
    for (int n = 0; n < 4; n++) acc[m][n] = (f32x4_t)(0.0f);

  f32x4_t  bv[2][2];
  short8_t af[2][4];

#define LOADB(p, j0)                                                        \
  {                                                                         \
    _Pragma("unroll") for (int jj = 0; jj < 2; jj++)                        \
        bv[p][jj] = *reinterpret_cast<const f32x4_t*>(                      \
            wi + (size_t)((j0) + jp * 2 + jj) * K_ + kq * 4);               \
  }
#define LOADA(p, j0)                                                        \
  {                                                                         \
    _Pragma("unroll") for (int m = 0; m < 4; m++)                           \
        af[p][m] = *reinterpret_cast<const short8_t*>(                      \
            cbf + (size_t)(arow + m * 16) * J_ + (j0) + lhi * 8);           \
  }
#define STOREB(buf, p)                                                      \
  {                                                                         \
    _Pragma("unroll") for (int kk = 0; kk < 4; kk++)                        \
        *reinterpret_cast<uint*>(&Bt[buf][kq * 4 + kk][jp * 2]) =           \
            pack2bf(bv[p][0][kk], bv[p][1][kk]);                            \
  }

  LOADB(0, 0);
  LOADA(0, 0);
  STOREB(0, 0);
  __syncthreads();

#pragma unroll
  for (int t = 0; t < 8; ++t) {
    const int cur = t & 1;
    const int nxt = cur ^ 1;
    if (t < 7) {
      LOADB(nxt, (t + 1) * 32);
      LOADA(nxt, (t + 1) * 32);
    }
    short8_t bfr[4];
#pragma unroll
    for (int n = 0; n < 4; n++)
      bfr[n] = *reinterpret_cast<const short8_t*>(
          &Bt[cur][n * 16 + lrow][lhi * 8]);
#pragma unroll
    for (int m = 0; m < 4; m++)
#pragma unroll
      for (int n = 0; n < 4; n++)
        acc[m][n] = __builtin_amdgcn_mfma_f32_16x16x32_bf16(
            af[cur][m], bfr[n], acc[m][n], 0, 0, 0);
    if (t < 7) STOREB(nxt, nxt);
    __syncthreads();
  }

#pragma unroll
  for (int m = 0; m < 4; m++) {
    const int brow = wave * 64 + m * 16 + lhi * 4;
#pragma unroll
    for (int n = 0; n < 4; n++) {
      const int kc = k0 + n * 16 + lrow;
      ushort* up = u + ((size_t)brow * I_ + i) * K_ + kc;
#pragma unroll
      for (int r = 0; r < 4; r++)
        up[(size_t)r * (I_ * K_)] = f2bf(acc[m][n][r]);
    }
  }
#undef LOADB
#undef LOADA
#undef STOREB
}

// ---------------------------------------------------------------------------
// Pass 2: out[a][b][k] = sum_i s[a][b][i] * u[b][i][k] + bias[k]
// (round-3 proven version, ~roofline) Grid (B, 2): block handles 4 a's.
// ---------------------------------------------------------------------------
__global__ __launch_bounds__(256) void pass2_kernel(
    const float* __restrict__ s, const ushort* __restrict__ u,
    const float* __restrict__ bias, float* __restrict__ out) {
  const int b   = blockIdx.x;
  const int a0  = blockIdx.y * 4;
  const int tid = threadIdx.x;
  __shared__ float s_l[4][I_];
  __shared__ float red[8][4][K_];

#pragma unroll
  for (int v = 0; v < 4; v++) {
    const int idx = tid + v * 256;
    const int a = idx >> 8, ii = idx & 255;
    s_l[a][ii] = s[((size_t)(a0 + a) * B_ + b) * I_ + ii];
  }
  __syncthreads();

  const int kb = (tid & 31) * 8;
  const int ig = tid >> 5;
  float acc[4][8];
#pragma unroll
  for (int a = 0; a < 4; a++)
#pragma unroll
    for (int q = 0; q < 8; q++) acc[a][q] = 0.0f;

  const ushort* ub = u + ((size_t)b * I_ + ig * 32) * K_ + kb;
  for (int ii = 0; ii < 32; ++ii) {
    const short8_t uv = *reinterpret_cast<const short8_t*>(ub + (size_t)ii * K_);
    float f[8];
#pragma unroll
    for (int q = 0; q < 8; q++) f[q] = bf2f((ushort)uv[q]);
    const int i = ig * 32 + ii;
#pragma unroll
    for (int a = 0; a < 4; a++) {
      const float sa = s_l[a][i];
#pragma unroll
      for (int q = 0; q < 8; q++) acc[a][q] += sa * f[q];
    }
  }

#pragma unroll
  for (int a = 0; a < 4; a++) {
    f32x4_t r0, r1;
#pragma unroll
    for (int q = 0; q < 4; q++) { r0[q] = acc[a][q]; r1[q] = acc[a][4 + q]; }
    *reinterpret_cast<f32x4_t*>(&red[ig][a][kb])     = r0;
    *reinterpret_cast<f32x4_t*>(&red[ig][a][kb + 4]) = r1;
  }
  __syncthreads();

#pragma unroll
  for (int v = 0; v < 4; v++) {
    const int k = tid;
    float sum = 0.0f;
#pragma unroll
    for (int g = 0; g < 8; g++) sum += red[g][v][k];
    out[((size_t)(a0 + v) * B_ + b) * K_ + k] = sum + bias[k];
  }
}

// ---------------------------------------------------------------------------
// Fallback (slow but correct, fp32).
// ---------------------------------------------------------------------------
__global__ __launch_bounds__(256) void fallback_kernel(
    const float* __restrict__ s, const float* __restrict__ cmat,
    const float* __restrict__ w, const float* __restrict__ bias,
    float* __restrict__ out) {
  const int b = blockIdx.x;
  const int k = threadIdx.x;
  __shared__ float c_l[J_];
  __shared__ float s_l[A_][I_];
  for (int idx = threadIdx.x; idx < J_; idx += 256) c_l[idx] = cmat[(size_t)b * J_ + idx];
  for (int idx = threadIdx.x; idx < A_ * I_; idx += 256) {
    const int a = idx >> 8;
    const int i = idx & 255;
    s_l[a][i] = s[(size_t)a * (B_ * I_) + (size_t)b * I_ + i];
  }
  __syncthreads();
  float acc[A_];
#pragma unroll
  for (int a = 0; a < A_; a++) acc[a] = 0.0f;
  for (int i = 0; i < I_; i++) {
    const float* wrow = w + (size_t)i * (J_ * K_) + k;
    float inner = 0.0f;
    for (int j = 0; j < J_; j++) inner += c_l[j] * wrow[(size_t)j * K_];
#pragma unroll
    for (int a = 0; a < A_; a++) acc[a] += s_l[a][i] * inner;
  }
#pragma unroll
  for (int a = 0; a < A_; a++)
    out[((size_t)a * B_ + b) * K_ + k] = acc[a] + bias[k];
}

extern "C" void kernel_launch(void* const* d_in, const int* in_sizes, int n_in,
                              void* d_out, int out_size, void* d_ws, size_t ws_size,
                              hipStream_t stream) {
  const float* s    = (const float*)d_in[0];  // (A,B,I)
  const float* cmat = (const float*)d_in[1];  // (B,J)
  const float* w    = (const float*)d_in[2];  // (I,J,K)
  const float* bias = (const float*)d_in[3];  // (K,)
  float* out = (float*)d_out;

  const size_t u_elems   = (size_t)B_ * I_ * K_;  // 16.7M halves
  const size_t wt_elems  = (size_t)I_ * J_ * K_;  // 16.7M halves
  const size_t cbf_elems = (size_t)B_ * J_;
  const size_t need_full = (u_elems + wt_elems + cbf_elems) * sizeof(ushort);
  const size_t need_mid  = (u_elems + cbf_elems) * sizeof(ushort);

  if (ws_size >= need_full) {
    ushort* u   = (ushort*)d_ws;
    ushort* wt  = (ushort*)d_ws + u_elems;
    ushort* cbf = (ushort*)d_ws + u_elems + wt_elems;
    prepass_c_kernel<<<dim3((B_ * J_) / (256 * 4)), dim3(256), 0, stream>>>(cmat, cbf);
    prepass_w_kernel<<<dim3(I_, 8), dim3(256), 0, stream>>>(w, wt);
    pass1_kernel<<<dim3(1024), dim3(256), 0, stream>>>(cbf, wt, u);
    pass2_kernel<<<dim3(B_, 2), dim3(256), 0, stream>>>(s, u, bias, out);
  } else if (ws_size >= need_mid) {
    ushort* u   = (ushort*)d_ws;
    ushort* cbf = (ushort*)d_ws + u_elems;
    prepass_c_kernel<<<dim3((B_ * J_) / (256 * 4)), dim3(256), 0, stream>>>(cmat, cbf);
    pass1_lds_kernel<<<dim3(I_, 4), dim3(256), 0, stream>>>(cbf, w, u);
    pass2_kernel<<<dim3(B_, 2), dim3(256), 0, stream>>>(s, u, bias, out);
  } else {
    fallback_kernel<<<dim3(B_), dim3(256), 0, stream>>>(s, cmat, w, bias, out);
  }
}

// Round 7
// 46.828 us; speedup vs baseline: 1.5971x; 1.2615x over previous
//
#include <hip/hip_runtime.h>
#include <hip/hip_bf16.h>

#define A_ 8
#define B_ 256
#define I_ 256
#define J_ 256
#define K_ 256

typedef __attribute__((ext_vector_type(8))) short short8_t;
typedef __attribute__((ext_vector_type(4))) float f32x4_t;

static __device__ __forceinline__ uint pack2bf(float a, float b) {
  float2 f2; f2.x = a; f2.y = b;
  __hip_bfloat162 h2 = __float22bfloat162_rn(f2);
  uint r;
  __builtin_memcpy(&r, &h2, 4);
  return r;
}

static __device__ __forceinline__ ushort f2bf(float f) {
  __hip_bfloat16 h = __float2bfloat16(f);
  ushort us;
  __builtin_memcpy(&us, &h, 2);
  return us;
}

static __device__ __forceinline__ float bf2f(ushort h) {
  uint u = ((uint)h) << 16;
  float f;
  __builtin_memcpy(&f, &u, 4);
  return f;
}

// ---------------------------------------------------------------------------
// Prepass C: cbf[b][j] = bf16(c[b][j])
// ---------------------------------------------------------------------------
__global__ __launch_bounds__(256) void prepass_c_kernel(
    const float* __restrict__ c, ushort* __restrict__ cbf) {
  const int idx = blockIdx.x * 256 + threadIdx.x;
  const f32x4_t v = *reinterpret_cast<const f32x4_t*>(c + (size_t)idx * 4);
  uint2 r;
  r.x = pack2bf(v[0], v[1]);
  r.y = pack2bf(v[2], v[3]);
  *reinterpret_cast<uint2*>(cbf + (size_t)idx * 4) = r;
}

// ---------------------------------------------------------------------------
// Pass 1: u[b][i][k] = sum_j c[b][j] * w[i][j][k]   (u stored bf16 [b][i][k])
// Grid (i, k-quarter) = (256,4). 256 thr = 4 waves, wave = 64(b) x 64(k).
// DEPTH-2 SOFTWARE PIPELINE (the fix for rounds 1-6's exposed latency):
//   iter t:  ds_read frags(t) | issue B-glob(t+2), A-glob(t+2) | MFMA(t)
//            | convert+ds_write B(t+1) | lgkmcnt(0); raw s_barrier
// Loads issued at t are consumed at t+2 (~2 iters ≈ 700+ cy) -> L2/L3
// latency covered. NO vmcnt(0) anywhere in the loop (no __syncthreads).
// A (cbf, 128KB, L2-hot) read as b128 frags directly from global.
// B (w fp32) read once chip-wide (64MB), reg-transposed to bf16 Bt[k][j].
// ---------------------------------------------------------------------------
#define LDK 40  // Bt row length in halves (80B)

__global__ __launch_bounds__(256, 3) void pass1_kernel(
    const ushort* __restrict__ cbf, const float* __restrict__ w,
    ushort* __restrict__ u) {
  const int i    = blockIdx.x;
  const int k0   = blockIdx.y * 64;
  const int tid  = threadIdx.x;
  const int lane = tid & 63;
  const int wave = tid >> 6;   // b-quadrant (0..3)
  const int lrow = lane & 15;
  const int lhi  = lane >> 4;  // 0..3

  __shared__ ushort Bt[2][64][LDK];  // [k-local][j-local] bf16, 10 KB

  const float* wi = w + (size_t)i * (J_ * K_) + k0;

  // B staging micro-tile: thread = (j-pair, k-quad)
  const int jp = tid & 15;  // j-local = jp*2 + jj
  const int kq = tid >> 4;  // k-local = kq*4 + kk

  const int arow = wave * 64 + lrow;  // A frag row (direct-from-global)

  f32x4_t acc[4][4];
#pragma unroll
  for (int m = 0; m < 4; m++)
#pragma unroll
    for (int n = 0; n < 4; n++) acc[m][n] = (f32x4_t)(0.0f);

  f32x4_t  bv[2][2];   // [slot][jj] : 4 consecutive k of j-rows jp*2, jp*2+1
  short8_t afr[2][4];  // [slot][m]  : A fragments

#define BGLOB(p, t)                                                         \
  {                                                                         \
    _Pragma("unroll") for (int jj = 0; jj < 2; jj++)                        \
        bv[p][jj] = *reinterpret_cast<const f32x4_t*>(                      \
            wi + (size_t)((t) * 32 + jp * 2 + jj) * K_ + kq * 4);           \
  }
#define ALOAD(p, t)                                                         \
  {                                                                         \
    _Pragma("unroll") for (int m = 0; m < 4; m++)                           \
        afr[p][m] = *reinterpret_cast<const short8_t*>(                     \
            cbf + (size_t)(arow + m * 16) * J_ + (t) * 32 + lhi * 8);       \
  }
#define STOREB(buf, p)                                                      \
  {                                                                         \
    _Pragma("unroll") for (int kk = 0; kk < 4; kk++)                        \
        *reinterpret_cast<uint*>(&Bt[buf][kq * 4 + kk][jp * 2]) =           \
            pack2bf(bv[p][0][kk], bv[p][1][kk]);                            \
  }

  // prologue: fill depth-2 pipeline; stage step 0 into LDS buf 0
  BGLOB(0, 0);
  BGLOB(1, 1);
  ALOAD(0, 0);
  ALOAD(1, 1);
  STOREB(0, 0);  // compiler waits bv[0] loads only
  asm volatile("s_waitcnt lgkmcnt(0)" ::: "memory");
  __builtin_amdgcn_s_barrier();

#pragma unroll
  for (int t = 0; t < 8; ++t) {
    const int cur = t & 1;
    // LDS -> B fragments for step t
    short8_t bfr[4];
#pragma unroll
    for (int n = 0; n < 4; n++)
      bfr[n] = *reinterpret_cast<const short8_t*>(
          &Bt[cur][n * 16 + lrow][lhi * 8]);
    // issue depth-2 prefetches (consumed at t+2)
    if (t < 6) BGLOB(cur, t + 2);  // bv[cur] was consumed by STOREB at t-1
    // MFMA for step t
#pragma unroll
    for (int m = 0; m < 4; m++)
#pragma unroll
      for (int n = 0; n < 4; n++)
        acc[m][n] = __builtin_amdgcn_mfma_f32_16x16x32_bf16(
            afr[cur][m], bfr[n], acc[m][n], 0, 0, 0);
    if (t < 6) ALOAD(cur, t + 2);  // afr[cur] just consumed
    if (t < 7) {
      STOREB(cur ^ 1, cur ^ 1);  // write step t+1 (loaded at t-1) into buf^1
      asm volatile("s_waitcnt lgkmcnt(0)" ::: "memory");
      __builtin_amdgcn_s_barrier();
    }
  }
#undef BGLOB
#undef ALOAD
#undef STOREB

  // epilogue: u[b][i][k] bf16
#pragma unroll
  for (int m = 0; m < 4; m++) {
    const int brow = wave * 64 + m * 16 + lhi * 4;
#pragma unroll
    for (int n = 0; n < 4; n++) {
      const int kc = k0 + n * 16 + lrow;
      ushort* up = u + ((size_t)brow * I_ + i) * K_ + kc;
#pragma unroll
      for (int r = 0; r < 4; r++)
        up[(size_t)r * (I_ * K_)] = f2bf(acc[m][n][r]);
    }
  }
}

// ---------------------------------------------------------------------------
// Pass 2: out[a][b][k] = sum_i s[a][b][i] * u[b][i][k] + bias[k]
// (round-3 proven version, ~roofline) Grid (B, 2): block handles 4 a's.
// ---------------------------------------------------------------------------
__global__ __launch_bounds__(256) void pass2_kernel(
    const float* __restrict__ s, const ushort* __restrict__ u,
    const float* __restrict__ bias, float* __restrict__ out) {
  const int b   = blockIdx.x;
  const int a0  = blockIdx.y * 4;
  const int tid = threadIdx.x;
  __shared__ float s_l[4][I_];
  __shared__ float red[8][4][K_];

#pragma unroll
  for (int v = 0; v < 4; v++) {
    const int idx = tid + v * 256;
    const int a = idx >> 8, ii = idx & 255;
    s_l[a][ii] = s[((size_t)(a0 + a) * B_ + b) * I_ + ii];
  }
  __syncthreads();

  const int kb = (tid & 31) * 8;
  const int ig = tid >> 5;
  float acc[4][8];
#pragma unroll
  for (int a = 0; a < 4; a++)
#pragma unroll
    for (int q = 0; q < 8; q++) acc[a][q] = 0.0f;

  const ushort* ub = u + ((size_t)b * I_ + ig * 32) * K_ + kb;
  for (int ii = 0; ii < 32; ++ii) {
    const short8_t uv = *reinterpret_cast<const short8_t*>(ub + (size_t)ii * K_);
    float f[8];
#pragma unroll
    for (int q = 0; q < 8; q++) f[q] = bf2f((ushort)uv[q]);
    const int i = ig * 32 + ii;
#pragma unroll
    for (int a = 0; a < 4; a++) {
      const float sa = s_l[a][i];
#pragma unroll
      for (int q = 0; q < 8; q++) acc[a][q] += sa * f[q];
    }
  }

#pragma unroll
  for (int a = 0; a < 4; a++) {
    f32x4_t r0, r1;
#pragma unroll
    for (int q = 0; q < 4; q++) { r0[q] = acc[a][q]; r1[q] = acc[a][4 + q]; }
    *reinterpret_cast<f32x4_t*>(&red[ig][a][kb])     = r0;
    *reinterpret_cast<f32x4_t*>(&red[ig][a][kb + 4]) = r1;
  }
  __syncthreads();

#pragma unroll
  for (int v = 0; v < 4; v++) {
    const int k = tid;
    float sum = 0.0f;
#pragma unroll
    for (int g = 0; g < 8; g++) sum += red[g][v][k];
    out[((size_t)(a0 + v) * B_ + b) * K_ + k] = sum + bias[k];
  }
}

// ---------------------------------------------------------------------------
// Fallback (slow but correct, fp32): used only if workspace is too small.
// ---------------------------------------------------------------------------
__global__ __launch_bounds__(256) void fallback_kernel(
    const float* __restrict__ s, const float* __restrict__ cmat,
    const float* __restrict__ w, const float* __restrict__ bias,
    float* __restrict__ out) {
  const int b = blockIdx.x;
  const int k = threadIdx.x;
  __shared__ float c_l[J_];
  __shared__ float s_l[A_][I_];
  for (int idx = threadIdx.x; idx < J_; idx += 256) c_l[idx] = cmat[(size_t)b * J_ + idx];
  for (int idx = threadIdx.x; idx < A_ * I_; idx += 256) {
    const int a = idx >> 8;
    const int i = idx & 255;
    s_l[a][i] = s[(size_t)a * (B_ * I_) + (size_t)b * I_ + i];
  }
  __syncthreads();
  float acc[A_];
#pragma unroll
  for (int a = 0; a < A_; a++) acc[a] = 0.0f;
  for (int i = 0; i < I_; i++) {
    const float* wrow = w + (size_t)i * (J_ * K_) + k;
    float inner = 0.0f;
    for (int j = 0; j < J_; j++) inner += c_l[j] * wrow[(size_t)j * K_];
#pragma unroll
    for (int a = 0; a < A_; a++) acc[a] += s_l[a][i] * inner;
  }
#pragma unroll
  for (int a = 0; a < A_; a++)
    out[((size_t)a * B_ + b) * K_ + k] = acc[a] + bias[k];
}

extern "C" void kernel_launch(void* const* d_in, const int* in_sizes, int n_in,
                              void* d_out, int out_size, void* d_ws, size_t ws_size,
                              hipStream_t stream) {
  const float* s    = (const float*)d_in[0];  // (A,B,I)
  const float* cmat = (const float*)d_in[1];  // (B,J)
  const float* w    = (const float*)d_in[2];  // (I,J,K)
  const float* bias = (const float*)d_in[3];  // (K,)
  float* out = (float*)d_out;

  const size_t u_elems   = (size_t)B_ * I_ * K_;  // 16.7M halves
  const size_t cbf_elems = (size_t)B_ * J_;
  const size_t need = (u_elems + cbf_elems) * sizeof(ushort);  // ~33.7 MB

  if (ws_size >= need) {
    ushort* u   = (ushort*)d_ws;
    ushort* cbf = (ushort*)d_ws + u_elems;
    prepass_c_kernel<<<dim3((B_ * J_) / (256 * 4)), dim3(256), 0, stream>>>(cmat, cbf);
    pass1_kernel<<<dim3(I_, 4), dim3(256), 0, stream>>>(cbf, w, u);
    pass2_kernel<<<dim3(B_, 2), dim3(256), 0, stream>>>(s, u, bias, out);
  } else {
    fallback_kernel<<<dim3(B_), dim3(256), 0, stream>>>(s, cmat, w, bias, out);
  }
}

// Round 8
// 46.812 us; speedup vs baseline: 1.5976x; 1.0003x over previous
//
#include <hip/hip_runtime.h>
#include <hip/hip_bf16.h>

#define A_ 8
#define B_ 256
#define I_ 256
#define J_ 256
#define K_ 256

typedef __attribute__((ext_vector_type(8))) short short8_t;
typedef __attribute__((ext_vector_type(4))) float f32x4_t;

static __device__ __forceinline__ uint pack2bf(float a, float b) {
  float2 f2; f2.x = a; f2.y = b;
  __hip_bfloat162 h2 = __float22bfloat162_rn(f2);
  uint r;
  __builtin_memcpy(&r, &h2, 4);
  return r;
}

static __device__ __forceinline__ ushort f2bf(float f) {
  __hip_bfloat16 h = __float2bfloat16(f);
  ushort us;
  __builtin_memcpy(&us, &h, 2);
  return us;
}

static __device__ __forceinline__ float bf2f(ushort h) {
  uint u = ((uint)h) << 16;
  float f;
  __builtin_memcpy(&f, &u, 4);
  return f;
}

// ---------------------------------------------------------------------------
// Prepass C: cbf[b][j] = bf16(c[b][j])
// ---------------------------------------------------------------------------
__global__ __launch_bounds__(256) void prepass_c_kernel(
    const float* __restrict__ c, ushort* __restrict__ cbf) {
  const int idx = blockIdx.x * 256 + threadIdx.x;
  const f32x4_t v = *reinterpret_cast<const f32x4_t*>(c + (size_t)idx * 4);
  uint2 r;
  r.x = pack2bf(v[0], v[1]);
  r.y = pack2bf(v[2], v[3]);
  *reinterpret_cast<uint2*>(cbf + (size_t)idx * 4) = r;
}

// ---------------------------------------------------------------------------
// Pass 1: u[b][i][k] = sum_j c[b][j] * w[i][j][k]   (u stored bf16 [b][i][k])
// NEW STRUCTURE (fix for the m97-small-N pathology of rounds 1-7):
//   grid (i=256, kh=2) = 512 blocks (2/CU). Block = ALL 256 b x 128 k x 1 i.
//   No j-loop over tiny tiles: the whole w[i][:,khalf] (128KB fp32) is staged
//   in 2 j-half phases with 16 independent dwordx4/thread (huge MLP) and only
//   TWO barriers in the entire kernel. Compute = 32 straight-line MFMA steps.
//   A (c) frags read directly from L2-hot cbf (loaded per kk, no LDS).
//   B tile in XOR-swizzled LDS [k][j]: chunk cid ^= (k&7) -> ds_write and
//   ds_read_b128 both 2-way bank (free), row stride 512B, 64KB total.
//   Stage(half1) loads issued BEFORE compute(half0), ds_written after (T14);
//   no race: halves occupy disjoint 16B chunks (cid 0-15 vs 16-31).
// ---------------------------------------------------------------------------
__global__ __launch_bounds__(256, 2) void pass1_kernel(
    const ushort* __restrict__ cbf, const float* __restrict__ w,
    ushort* __restrict__ u) {
  const int i    = blockIdx.x;
  const int kh   = blockIdx.y;      // k half (0/1)
  const int tid  = threadIdx.x;
  const int lane = tid & 63;
  const int wave = tid >> 6;        // b-quadrant (0..3)
  const int lrow = lane & 15;
  const int lhi  = lane >> 4;       // 0..3

  __shared__ __align__(16) char Bt[128 * 512];  // swizzled [k][j] bf16, 64KB

  const float* wi = w + (size_t)i * (J_ * K_) + kh * 128;

  // stage coords: thread = (j-pair jp, k-chunk kc=wave)
  const int jp = tid & 63;          // j-local pair: rows jp*2, jp*2+1
  const int kc = tid >> 6;          // k chunk of 32: klocal = kc*32 + ...
  const int arow = wave * 64 + lrow;

  f32x4_t acc[4][8];
#pragma unroll
  for (int m = 0; m < 4; m++)
#pragma unroll
    for (int n = 0; n < 8; n++) acc[m][n] = (f32x4_t)(0.0f);

  f32x4_t sv[8];  // one stage tranche: 2 j-rows x 16 k

  // GLOAD(jh, ko): load rows {jp*2, jp*2+1} of j-half jh, k = kc*32+ko..+16
#define GLOAD(jh, ko)                                                       \
  {                                                                         \
    _Pragma("unroll") for (int jj = 0; jj < 2; jj++)                        \
        _Pragma("unroll") for (int q = 0; q < 4; q++)                       \
        sv[jj * 4 + q] = *reinterpret_cast<const f32x4_t*>(                 \
            wi + (size_t)((jh) * 128 + jp * 2 + jj) * K_ + kc * 32 + (ko) + \
            q * 4);                                                         \
  }
  // STORE(jh, ko): pack j-pairs -> swizzled LDS uint writes (2-way banks)
#define STORE(jh, ko)                                                       \
  {                                                                         \
    const int jc  = (jh) * 64 + jp;                                         \
    const int cid = jc >> 2;                                                \
    const int wb  = (jc & 3) * 4;                                           \
    _Pragma("unroll") for (int q = 0; q < 16; q++) {                        \
      const int k = kc * 32 + (ko) + q;                                     \
      *reinterpret_cast<uint*>(                                             \
          Bt + k * 512 + ((cid ^ (q & 7)) * 16) + wb) =                     \
          pack2bf(sv[(q >> 2)][q & 3], sv[4 + (q >> 2)][q & 3]);            \
    }                                                                       \
  }
  // COMPUTE(jh, kk): one K-step: 4 A-frags (from cbf), 8 B-frags (LDS), 32 MFMA
#define COMPUTE(jh, kk)                                                     \
  {                                                                         \
    short8_t af[4];                                                         \
    _Pragma("unroll") for (int m = 0; m < 4; m++)                           \
        af[m] = *reinterpret_cast<const short8_t*>(                         \
            cbf + (size_t)(arow + m * 16) * J_ + (jh) * 128 + (kk) * 32 +   \
            lhi * 8);                                                       \
    short8_t bf[8];                                                         \
    _Pragma("unroll") for (int n = 0; n < 8; n++) {                         \
      const int row = n * 16 + lrow;                                        \
      const int cid = ((jh) * 16 + (kk) * 4 + lhi) ^ (lrow & 7);            \
      bf[n] = *reinterpret_cast<const short8_t*>(Bt + row * 512 + cid * 16);\
    }                                                                       \
    _Pragma("unroll") for (int m = 0; m < 4; m++)                           \
        _Pragma("unroll") for (int n = 0; n < 8; n++)                       \
        acc[m][n] = __builtin_amdgcn_mfma_f32_16x16x32_bf16(                \
            af[m], bf[n], acc[m][n], 0, 0, 0);                              \
  }

  // prologue: stage j-half 0
  GLOAD(0, 0);  STORE(0, 0);
  GLOAD(0, 16); STORE(0, 16);
  __syncthreads();

  // half 0 compute, half 1 stage overlapped (disjoint swizzled chunks)
  GLOAD(1, 0);
  COMPUTE(0, 0);
  COMPUTE(0, 1);
  STORE(1, 0);
  GLOAD(1, 16);
  COMPUTE(0, 2);
  COMPUTE(0, 3);
  STORE(1, 16);
  __syncthreads();

  // half 1 compute
  COMPUTE(1, 0);
  COMPUTE(1, 1);
  COMPUTE(1, 2);
  COMPUTE(1, 3);

#undef GLOAD
#undef STORE
#undef COMPUTE

  // epilogue: u[b][i][k] bf16
#pragma unroll
  for (int m = 0; m < 4; m++) {
    const int brow = wave * 64 + m * 16 + lhi * 4;
#pragma unroll
    for (int n = 0; n < 8; n++) {
      const int kc_g = kh * 128 + n * 16 + lrow;
      ushort* up = u + ((size_t)brow * I_ + i) * K_ + kc_g;
#pragma unroll
      for (int r = 0; r < 4; r++)
        up[(size_t)r * (I_ * K_)] = f2bf(acc[m][n][r]);
    }
  }
}

// ---------------------------------------------------------------------------
// Pass 2: out[a][b][k] = sum_i s[a][b][i] * u[b][i][k] + bias[k]
// (round-3 proven version, at its ~40MB roofline) Grid (B, 2).
// ---------------------------------------------------------------------------
__global__ __launch_bounds__(256) void pass2_kernel(
    const float* __restrict__ s, const ushort* __restrict__ u,
    const float* __restrict__ bias, float* __restrict__ out) {
  const int b   = blockIdx.x;
  const int a0  = blockIdx.y * 4;
  const int tid = threadIdx.x;
  __shared__ float s_l[4][I_];
  __shared__ float red[8][4][K_];

#pragma unroll
  for (int v = 0; v < 4; v++) {
    const int idx = tid + v * 256;
    const int a = idx >> 8, ii = idx & 255;
    s_l[a][ii] = s[((size_t)(a0 + a) * B_ + b) * I_ + ii];
  }
  __syncthreads();

  const int kb = (tid & 31) * 8;
  const int ig = tid >> 5;
  float acc[4][8];
#pragma unroll
  for (int a = 0; a < 4; a++)
#pragma unroll
    for (int q = 0; q < 8; q++) acc[a][q] = 0.0f;

  const ushort* ub = u + ((size_t)b * I_ + ig * 32) * K_ + kb;
  for (int ii = 0; ii < 32; ++ii) {
    const short8_t uv = *reinterpret_cast<const short8_t*>(ub + (size_t)ii * K_);
    float f[8];
#pragma unroll
    for (int q = 0; q < 8; q++) f[q] = bf2f((ushort)uv[q]);
    const int i = ig * 32 + ii;
#pragma unroll
    for (int a = 0; a < 4; a++) {
      const float sa = s_l[a][i];
#pragma unroll
      for (int q = 0; q < 8; q++) acc[a][q] += sa * f[q];
    }
  }

#pragma unroll
  for (int a = 0; a < 4; a++) {
    f32x4_t r0, r1;
#pragma unroll
    for (int q = 0; q < 4; q++) { r0[q] = acc[a][q]; r1[q] = acc[a][4 + q]; }
    *reinterpret_cast<f32x4_t*>(&red[ig][a][kb])     = r0;
    *reinterpret_cast<f32x4_t*>(&red[ig][a][kb + 4]) = r1;
  }
  __syncthreads();

#pragma unroll
  for (int v = 0; v < 4; v++) {
    const int k = tid;
    float sum = 0.0f;
#pragma unroll
    for (int g = 0; g < 8; g++) sum += red[g][v][k];
    out[((size_t)(a0 + v) * B_ + b) * K_ + k] = sum + bias[k];
  }
}

// ---------------------------------------------------------------------------
// Fallback (slow but correct, fp32): used only if workspace is too small.
// ---------------------------------------------------------------------------
__global__ __launch_bounds__(256) void fallback_kernel(
    const float* __restrict__ s, const float* __restrict__ cmat,
    const float* __restrict__ w, const float* __restrict__ bias,
    float* __restrict__ out) {
  const int b = blockIdx.x;
  const int k = threadIdx.x;
  __shared__ float c_l[J_];
  __shared__ float s_l[A_][I_];
  for (int idx = threadIdx.x; idx < J_; idx += 256) c_l[idx] = cmat[(size_t)b * J_ + idx];
  for (int idx = threadIdx.x; idx < A_ * I_; idx += 256) {
    const int a = idx >> 8;
    const int i = idx & 255;
    s_l[a][i] = s[(size_t)a * (B_ * I_) + (size_t)b * I_ + i];
  }
  __syncthreads();
  float acc[A_];
#pragma unroll
  for (int a = 0; a < A_; a++) acc[a] = 0.0f;
  for (int i = 0; i < I_; i++) {
    const float* wrow = w + (size_t)i * (J_ * K_) + k;
    float inner = 0.0f;
    for (int j = 0; j < J_; j++) inner += c_l[j] * wrow[(size_t)j * K_];
#pragma unroll
    for (int a = 0; a < A_; a++) acc[a] += s_l[a][i] * inner;
  }
#pragma unroll
  for (int a = 0; a < A_; a++)
    out[((size_t)a * B_ + b) * K_ + k] = acc[a] + bias[k];
}

extern "C" void kernel_launch(void* const* d_in, const int* in_sizes, int n_in,
                              void* d_out, int out_size, void* d_ws, size_t ws_size,
                              hipStream_t stream) {
  const float* s    = (const float*)d_in[0];  // (A,B,I)
  const float* cmat = (const float*)d_in[1];  // (B,J)
  const float* w    = (const float*)d_in[2];  // (I,J,K)
  const float* bias = (const float*)d_in[3];  // (K,)
  float* out = (float*)d_out;

  const size_t u_elems   = (size_t)B_ * I_ * K_;  // 16.7M halves
  const size_t cbf_elems = (size_t)B_ * J_;
  const size_t need = (u_elems + cbf_elems) * sizeof(ushort);  // ~33.7 MB

  if (ws_size >= need) {
    ushort* u   = (ushort*)d_ws;
    ushort* cbf = (ushort*)d_ws + u_elems;
    prepass_c_kernel<<<dim3((B_ * J_) / (256 * 4)), dim3(256), 0, stream>>>(cmat, cbf);
    pass1_kernel<<<dim3(I_, 2), dim3(256), 0, stream>>>(cbf, w, u);
    pass2_kernel<<<dim3(B_, 2), dim3(256), 0, stream>>>(s, u, bias, out);
  } else {
    fallback_kernel<<<dim3(B_), dim3(256), 0, stream>>>(s, cmat, w, bias, out);
  }
}

// Round 10
// 43.855 us; speedup vs baseline: 1.7053x; 1.0674x over previous
//
#include <hip/hip_runtime.h>
#include <hip/hip_bf16.h>

#define A_ 8
#define B_ 256
#define I_ 256
#define J_ 256
#define K_ 256

typedef __attribute__((ext_vector_type(8))) short short8_t;
typedef __attribute__((ext_vector_type(4))) float f32x4_t;

static __device__ __forceinline__ uint pack2bf(float a, float b) {
  float2 f2; f2.x = a; f2.y = b;
  __hip_bfloat162 h2 = __float22bfloat162_rn(f2);
  uint r;
  __builtin_memcpy(&r, &h2, 4);
  return r;
}

static __device__ __forceinline__ ushort f2bf(float f) {
  __hip_bfloat16 h = __float2bfloat16(f);
  ushort us;
  __builtin_memcpy(&us, &h, 2);
  return us;
}

static __device__ __forceinline__ float bf2f(ushort h) {
  uint u = ((uint)h) << 16;
  float f;
  __builtin_memcpy(&f, &u, 4);
  return f;
}

// ---------------------------------------------------------------------------
// Prepass C: cbf[b][j] = bf16(c[b][j])
// ---------------------------------------------------------------------------
__global__ __launch_bounds__(256) void prepass_c_kernel(
    const float* __restrict__ c, ushort* __restrict__ cbf) {
  const int idx = blockIdx.x * 256 + threadIdx.x;
  const f32x4_t v = *reinterpret_cast<const f32x4_t*>(c + (size_t)idx * 4);
  uint2 r;
  r.x = pack2bf(v[0], v[1]);
  r.y = pack2bf(v[2], v[3]);
  *reinterpret_cast<uint2*>(cbf + (size_t)idx * 4) = r;
}

// ---------------------------------------------------------------------------
// Pass 1: u[b][i][k] = sum_j c[b][j] * w[i][j][k]   (u stored bf16 [b][i][k])
// CONTIGUOUS-READ STRUCTURE (fix for rounds 1-8's ~1.6 TB/s strided-read
// wall): every w-load wave-instruction covers ONE FULL 1KB row of w[i]
// (64 lanes x dwordx4). Transpose j->register happens in LDS via the
// round-1-PROVEN scalar-read fragment pattern (no tr16).
// Grid = 256 blocks (one per i, 1/CU). 512 thr = 8 waves = 4 b-quads x 2
// k-halves; per-wave output 64b x 128k, acc[4][8].
// LDS Wl[256][258] ushort (129 KB): row stride 258 -> 8-row offset = +8
// banks -> e-loop frag reads conflict-free. Two j-half phases, one barrier;
// half-1 staged between MFMA steps (T14 issue-early/write-late).
// ---------------------------------------------------------------------------
__global__ __launch_bounds__(512, 1) void pass1_kernel(
    const ushort* __restrict__ cbf, const float* __restrict__ w,
    ushort* __restrict__ u) {
  const int i    = blockIdx.x;
  const int tid  = threadIdx.x;
  const int lane = tid & 63;
  const int wv   = tid >> 6;   // 0..7
  const int wb   = wv & 3;     // b-quadrant
  const int wk   = wv >> 2;    // k-half
  const int lrow = lane & 15;
  const int lhi  = lane >> 4;  // 0..3

  __shared__ ushort Wl[256][258];  // [j][k], 129 KB

  const float* wi = w + (size_t)i * (J_ * K_);
  const int arow = wb * 64 + lrow;

  f32x4_t acc[4][8];
#pragma unroll
  for (int m = 0; m < 4; m++)
#pragma unroll
    for (int n = 0; n < 8; n++) acc[m][n] = (f32x4_t)(0.0f);

  f32x4_t sA[8], sB[8];

  // load CNT full rows starting at row r0 (one wave-instr = one 1KB row)
#define STAGE(r0, sq, CNT)                                                  \
  {                                                                         \
    _Pragma("unroll") for (int q = 0; q < (CNT); q++)                       \
        sq[q] = *reinterpret_cast<const f32x4_t*>(                          \
            wi + (size_t)((r0) + q) * K_ + 4 * lane);                       \
  }
#define WRITE(r0, sq, CNT)                                                  \
  {                                                                         \
    _Pragma("unroll") for (int q = 0; q < (CNT); q++) {                     \
      uint2 val;                                                            \
      val.x = pack2bf(sq[q][0], sq[q][1]);                                  \
      val.y = pack2bf(sq[q][2], sq[q][3]);                                  \
      *reinterpret_cast<uint2*>(&Wl[(r0) + q][4 * lane]) = val;             \
    }                                                                       \
  }
  // one K-step (j-tile t*32..+32): R1-proven fragment addressing
#define STEP(t)                                                             \
  {                                                                         \
    short8_t af[4];                                                         \
    _Pragma("unroll") for (int m = 0; m < 4; m++)                           \
        af[m] = *reinterpret_cast<const short8_t*>(                         \
            cbf + (size_t)(arow + m * 16) * J_ + (t) * 32 + lhi * 8);       \
    short8_t bf[8];                                                         \
    _Pragma("unroll") for (int n = 0; n < 8; n++) {                         \
      const int col = wk * 128 + n * 16 + lrow;                             \
      _Pragma("unroll") for (int e = 0; e < 8; e++)                         \
          bf[n][e] = (short)Wl[(t) * 32 + lhi * 8 + e][col];                \
    }                                                                       \
    _Pragma("unroll") for (int m = 0; m < 4; m++)                           \
        _Pragma("unroll") for (int n = 0; n < 8; n++)                       \
        acc[m][n] = __builtin_amdgcn_mfma_f32_16x16x32_bf16(                \
            af[m], bf[n], acc[m][n], 0, 0, 0);                              \
  }

  // --- phase 0: stage j-half 0 (wave wv: rows wv*16..+16) ---
  const int h0 = wv * 16;
  STAGE(h0, sA, 8);
  STAGE(h0 + 8, sB, 8);
  WRITE(h0, sA, 8);
  WRITE(h0 + 8, sB, 8);
  __syncthreads();

  // --- steps 0-3 on j<128, half-1 staged in 4-row tranches between steps ---
  const int h1 = 128 + wv * 16;
  STAGE(h1, sA, 4);
  STEP(0);
  WRITE(h1, sA, 4);
  STAGE(h1 + 4, sB, 4);
  STEP(1);
  WRITE(h1 + 4, sB, 4);
  STAGE(h1 + 8, sA, 4);
  STEP(2);
  WRITE(h1 + 8, sA, 4);
  STAGE(h1 + 12, sB, 4);
  STEP(3);
  WRITE(h1 + 12, sB, 4);
  __syncthreads();

  // --- steps 4-7 on j>=128 ---
  STEP(4);
  STEP(5);
  STEP(6);
  STEP(7);

#undef STAGE
#undef WRITE
#undef STEP

  // epilogue: u[b][i][k] bf16 (mapping identical to rounds 3/7)
#pragma unroll
  for (int m = 0; m < 4; m++) {
    const int brow = wb * 64 + m * 16 + lhi * 4;
#pragma unroll
    for (int n = 0; n < 8; n++) {
      const int kc = wk * 128 + n * 16 + lrow;
      ushort* up = u + ((size_t)brow * I_ + i) * K_ + kc;
#pragma unroll
      for (int r = 0; r < 4; r++)
        up[(size_t)r * (I_ * K_)] = f2bf(acc[m][n][r]);
    }
  }
}

// ---------------------------------------------------------------------------
// Pass 2: out[a][b][k] = sum_i s[a][b][i] * u[b][i][k] + bias[k]
// (round-3 proven version, at its ~40MB roofline) Grid (B, 2).
// ---------------------------------------------------------------------------
__global__ __launch_bounds__(256) void pass2_kernel(
    const float* __restrict__ s, const ushort* __restrict__ u,
    const float* __restrict__ bias, float* __restrict__ out) {
  const int b   = blockIdx.x;
  const int a0  = blockIdx.y * 4;
  const int tid = threadIdx.x;
  __shared__ float s_l[4][I_];
  __shared__ float red[8][4][K_];

#pragma unroll
  for (int v = 0; v < 4; v++) {
    const int idx = tid + v * 256;
    const int a = idx >> 8, ii = idx & 255;
    s_l[a][ii] = s[((size_t)(a0 + a) * B_ + b) * I_ + ii];
  }
  __syncthreads();

  const int kb = (tid & 31) * 8;
  const int ig = tid >> 5;
  float acc[4][8];
#pragma unroll
  for (int a = 0; a < 4; a++)
#pragma unroll
    for (int q = 0; q < 8; q++) acc[a][q] = 0.0f;

  const ushort* ub = u + ((size_t)b * I_ + ig * 32) * K_ + kb;
  for (int ii = 0; ii < 32; ++ii) {
    const short8_t uv = *reinterpret_cast<const short8_t*>(ub + (size_t)ii * K_);
    float f[8];
#pragma unroll
    for (int q = 0; q < 8; q++) f[q] = bf2f((ushort)uv[q]);
    const int i = ig * 32 + ii;
#pragma unroll
    for (int a = 0; a < 4; a++) {
      const float sa = s_l[a][i];
#pragma unroll
      for (int q = 0; q < 8; q++) acc[a][q] += sa * f[q];
    }
  }

#pragma unroll
  for (int a = 0; a < 4; a++) {
    f32x4_t r0, r1;
#pragma unroll
    for (int q = 0; q < 4; q++) { r0[q] = acc[a][q]; r1[q] = acc[a][4 + q]; }
    *reinterpret_cast<f32x4_t*>(&red[ig][a][kb])     = r0;
    *reinterpret_cast<f32x4_t*>(&red[ig][a][kb + 4]) = r1;
  }
  __syncthreads();

#pragma unroll
  for (int v = 0; v < 4; v++) {
    const int k = tid;
    float sum = 0.0f;
#pragma unroll
    for (int g = 0; g < 8; g++) sum += red[g][v][k];
    out[((size_t)(a0 + v) * B_ + b) * K_ + k] = sum + bias[k];
  }
}

// ---------------------------------------------------------------------------
// Fallback (slow but correct, fp32): used only if workspace is too small.
// ---------------------------------------------------------------------------
__global__ __launch_bounds__(256) void fallback_kernel(
    const float* __restrict__ s, const float* __restrict__ cmat,
    const float* __restrict__ w, const float* __restrict__ bias,
    float* __restrict__ out) {
  const int b = blockIdx.x;
  const int k = threadIdx.x;
  __shared__ float c_l[J_];
  __shared__ float s_l[A_][I_];
  for (int idx = threadIdx.x; idx < J_; idx += 256) c_l[idx] = cmat[(size_t)b * J_ + idx];
  for (int idx = threadIdx.x; idx < A_ * I_; idx += 256) {
    const int a = idx >> 8;
    const int i = idx & 255;
    s_l[a][i] = s[(size_t)a * (B_ * I_) + (size_t)b * I_ + i];
  }
  __syncthreads();
  float acc[A_];
#pragma unroll
  for (int a = 0; a < A_; a++) acc[a] = 0.0f;
  for (int i = 0; i < I_; i++) {
    const float* wrow = w + (size_t)i * (J_ * K_) + k;
    float inner = 0.0f;
    for (int j = 0; j < J_; j++) inner += c_l[j] * wrow[(size_t)j * K_];
#pragma unroll
    for (int a = 0; a < A_; a++) acc[a] += s_l[a][i] * inner;
  }
#pragma unroll
  for (int a = 0; a < A_; a++)
    out[((size_t)a * B_ + b) * K_ + k] = acc[a] + bias[k];
}

extern "C" void kernel_launch(void* const* d_in, const int* in_sizes, int n_in,
                              void* d_out, int out_size, void* d_ws, size_t ws_size,
                              hipStream_t stream) {
  const float* s    = (const float*)d_in[0];  // (A,B,I)
  const float* cmat = (const float*)d_in[1];  // (B,J)
  const float* w    = (const float*)d_in[2];  // (I,J,K)
  const float* bias = (const float*)d_in[3];  // (K,)
  float* out = (float*)d_out;

  const size_t u_elems   = (size_t)B_ * I_ * K_;  // 16.7M halves
  const size_t cbf_elems = (size_t)B_ * J_;
  const size_t need = (u_elems + cbf_elems) * sizeof(ushort);  // ~33.7 MB

  if (ws_size >= need) {
    ushort* u   = (ushort*)d_ws;
    ushort* cbf = (ushort*)d_ws + u_elems;
    prepass_c_kernel<<<dim3((B_ * J_) / (256 * 4)), dim3(256), 0, stream>>>(cmat, cbf);
    pass1_kernel<<<dim3(I_), dim3(512), 0, stream>>>(cbf, w, u);
    pass2_kernel<<<dim3(B_, 2), dim3(256), 0, stream>>>(s, u, bias, out);
  } else {
    fallback_kernel<<<dim3(B_), dim3(256), 0, stream>>>(s, cmat, w, bias, out);
  }
}